// Round 7
// baseline (1005.465 us; speedup 1.0000x reference)
//
#include <hip/hip_runtime.h>
#include <hip/hip_fp16.h>
#include <math.h>

// SO3 DiT layer, MI355X fp32. N=6000, E=72000, P=2, L=2, M=9, F=64, H=4, DH=16
// R3: coalesced LDS staging for edge/proj GEMMs. 1370 -> 1080 us.
// R6: un-fused MLP, lane-coalesced h. 1285 -> 976 us.
// R7: k_edge is VALU-issue-bound (VALUBusy 76%, 1152 v_fma/edge/lane for the
// eq+ev GEMMs = 67 us floor, paying 255 us). Halve instruction count with
// v_dot2_f32_f16 (2 MACs/instr, fp32 accum): fe staged fp16 in LDS (18 KB),
// weights as 32 half2 VGPRs per matrix (VGPR 104 -> ~75, occupancy up).

#define NN 6000
#define EE 72000

#if defined(__has_builtin)
#if __has_builtin(__builtin_amdgcn_fdot2)
#define HAS_FDOT2 1
#else
#define HAS_FDOT2 0
#endif
#else
#define HAS_FDOT2 0
#endif

typedef _Float16 half2_t __attribute__((ext_vector_type(2)));

__device__ __forceinline__ half2_t u2h(unsigned u) {
  union { unsigned u; half2_t h; } c;
  c.u = u;
  return c.h;
}
__device__ __forceinline__ float fdot2f(half2_t a, half2_t b, float c) {
#if HAS_FDOT2
  return __builtin_amdgcn_fdot2(a, b, c, false);
#else
  return c + (float)a.x * (float)b.x + (float)a.y * (float)b.y;
#endif
}

__device__ __forceinline__ float wsum(float v) {
#pragma unroll
  for (int o = 32; o >= 1; o >>= 1) v += __shfl_xor(v, o, 64);
  return v;
}
__device__ __forceinline__ int deg_of(int m) { return (m == 0) ? 0 : ((m < 4) ? 1 : 2); }
// order-preserving float->uint for atomicMax-based segment max
__device__ __forceinline__ unsigned fenc(float x) {
  unsigned u = __float_as_uint(x);
  return (u & 0x80000000u) ? ~u : (u | 0x80000000u);
}
__device__ __forceinline__ float fdec(unsigned k) {
  unsigned u = (k & 0x80000000u) ? (k & 0x7fffffffu) : ~k;
  return __uint_as_float(u);
}

// ---------------- K1a: LayerNorm(T=64) + SiLU, one wave per node ----------------
__global__ __launch_bounds__(256) void k_ln_t(const float* __restrict__ ft,
                                              const float* __restrict__ lns,
                                              const float* __restrict__ lnb,
                                              float* __restrict__ sbuf) {
  int w = (blockIdx.x * 256 + threadIdx.x) >> 6;  // node, exact 6000
  int lane = threadIdx.x & 63;
  float t = ft[(size_t)w * 64 + lane];
  float mu = wsum(t) * (1.f / 64.f);
  float d = t - mu;
  float var = wsum(d * d) * (1.f / 64.f);
  float cin = d * rsqrtf(var + 1e-6f) * lns[lane] + lnb[lane];
  sbuf[(size_t)w * 64 + lane] = cin / (1.f + expf(-cin));
}

// ---------------- K1b: c = silu @ W_c + b_c  (64 -> 1664), 8 nodes/block ----------------
__global__ __launch_bounds__(256) void k_cond_mm(const float* __restrict__ sbuf,
                                                 const float* __restrict__ Wc,
                                                 const float* __restrict__ bc,
                                                 float* __restrict__ c) {
  __shared__ __align__(16) float st[8 * 64];  // 2 KB
  int n0 = blockIdx.x * 8;  // 750 blocks
  for (int i = threadIdx.x; i < 512; i += 256) st[i] = sbuf[(size_t)n0 * 64 + i];
  __syncthreads();
  for (int jj = threadIdx.x; jj < 1664; jj += 256) {
    float acc[8] = {0, 0, 0, 0, 0, 0, 0, 0};
#pragma unroll 8
    for (int k2 = 0; k2 < 64; k2++) {
      float wv = Wc[(size_t)k2 * 1664 + jj];
#pragma unroll
      for (int nd = 0; nd < 8; nd++) acc[nd] += st[nd * 64 + k2] * wv;
    }
    float b = bc[jj];
#pragma unroll
    for (int nd = 0; nd < 8; nd++) c[(size_t)(n0 + nd) * 1664 + jj] = acc[nd] + b;
  }
}

// ---------------- K2/K8: eqv layernorm + modulate, one wave per (n,p) ----------------
__global__ __launch_bounds__(256) void k_lnmod(const float* __restrict__ xin,
                                               const float* __restrict__ c,
                                               float* __restrict__ xout,
                                               int goff, int boff) {
  int w = (blockIdx.x * 256 + threadIdx.x) >> 6;  // (n,p) pair, exact 12000
  int lane = threadIdx.x & 63;
  int n = w >> 1, p = w & 1;
  const float* xb = xin + (size_t)w * 576 + lane;
  float x0 = xb[0], x1 = xb[64], x2 = xb[128], x3 = xb[192], x4 = xb[256];
  float x5 = xb[320], x6 = xb[384], x7 = xb[448], x8 = xb[512];
  float mu = wsum(x0) * (1.f / 64.f);
  x0 -= mu;
  float n20 = x0 * x0;
  float n21 = (x1 * x1 + x2 * x2 + x3 * x3) * (1.f / 3.f);
  float n22 = (x4 * x4 + x5 * x5 + x6 * x6 + x7 * x7 + x8 * x8) * (1.f / 5.f);
  n20 = wsum(n20) * (1.f / 64.f);
  n21 = wsum(n21) * (1.f / 64.f);
  n22 = wsum(n22) * (1.f / 64.f);
  float i0 = rsqrtf(n20 + 1e-6f), i1 = rsqrtf(n21 + 1e-6f), i2 = rsqrtf(n22 + 1e-6f);
  const float* cb = c + (size_t)n * 1664;
  float g0 = 1.f + cb[goff + p * 192 + lane];
  float g1 = 1.f + cb[goff + p * 192 + 64 + lane];
  float g2 = 1.f + cb[goff + p * 192 + 128 + lane];
  float bsh = cb[boff + lane];
  float* ob = xout + (size_t)w * 576 + lane;
  ob[0] = x0 * i0 * g0 + bsh;
  ob[64] = x1 * i1 * g1;
  ob[128] = x2 * i1 * g1;
  ob[192] = x3 * i1 * g1;
  ob[256] = x4 * i2 * g2;
  ob[320] = x5 * i2 * g2;
  ob[384] = x6 * i2 * g2;
  ob[448] = x7 * i2 * g2;
  ob[512] = x8 * i2 * g2;
}

// ---------------- CSR build: count, scan, fill ----------------
__global__ __launch_bounds__(256) void k_count(const int* __restrict__ dst_idx,
                                               const float* __restrict__ cutoff,
                                               float* __restrict__ cnt,
                                               float* __restrict__ cutsum) {
  int e = blockIdx.x * 256 + threadIdx.x;
  if (e >= EE) return;
  int d = dst_idx[e];
  unsafeAtomicAdd(cnt + d, 1.f);
  unsafeAtomicAdd(cutsum + d, cutoff[e]);
}

__global__ __launch_bounds__(1024) void k_scan(const float* __restrict__ cnt,
                                               int* __restrict__ rowptr,
                                               int* __restrict__ fillc) {
  __shared__ int part[1024];
  int t = threadIdx.x;
  int base = t * 6;  // 1024*6 = 6144 >= 6000
  int lc[6];
  int s = 0;
#pragma unroll
  for (int i = 0; i < 6; i++) {
    int idx = base + i;
    int vv = (idx < NN) ? (int)(cnt[idx] + 0.5f) : 0;
    lc[i] = s;
    s += vv;
  }
  part[t] = s;
  __syncthreads();
  for (int o = 1; o < 1024; o <<= 1) {
    int vv = (t >= o) ? part[t - o] : 0;
    __syncthreads();
    part[t] += vv;
    __syncthreads();
  }
  int ex = (t == 0) ? 0 : part[t - 1];
#pragma unroll
  for (int i = 0; i < 6; i++) {
    int idx = base + i;
    if (idx < NN) {
      int p = ex + lc[i];
      rowptr[idx] = p;
      fillc[idx] = p;
    }
  }
  if (t == 1023) rowptr[NN] = part[1023];  // == EE
}

__global__ __launch_bounds__(256) void k_fill(const int* __restrict__ dst_idx,
                                              const int* __restrict__ src_idx,
                                              const float* __restrict__ cutoff,
                                              int* __restrict__ fillc,
                                              int* __restrict__ eids,
                                              int* __restrict__ dsts,
                                              int* __restrict__ srcs,
                                              float* __restrict__ cuts) {
  int e = blockIdx.x * 256 + threadIdx.x;
  if (e >= EE) return;
  int d = dst_idx[e];
  int pos = atomicAdd(fillc + d, 1);
  eids[pos] = e;
  dsts[pos] = d;
  srcs[pos] = src_idx[e];
  cuts[pos] = cutoff[e];
}

// ---------------- K3: fused q/k/v projection, LDS-tiled, fp16 out ----------------
// grid (375, 18), 192 threads: wave = one of {q,k,v}; 16 nodes/block staged once.
__global__ __launch_bounds__(192) void k_qkv2(const float* __restrict__ xpre,
                                              const float* __restrict__ Wq,
                                              const float* __restrict__ Wk,
                                              const float* __restrict__ Wv,
                                              __half* __restrict__ qh,
                                              __half* __restrict__ kh,
                                              __half* __restrict__ vh) {
  __shared__ __align__(16) float xt[16 * 64];  // 4 KB
  int pm = blockIdx.y;
  int p = pm / 9, dm = deg_of(pm % 9);
  int n0 = blockIdx.x * 16;
  int mat = threadIdx.x >> 6;  // wave-uniform: 0=q 1=k 2=v
  int g = threadIdx.x & 63;
  for (int i = threadIdx.x; i < 1024; i += 192) {
    int r = i >> 6, f = i & 63;
    xt[i] = xpre[((size_t)(n0 + r) * 18 + pm) * 64 + f];
  }
  const float* Wsel = (mat == 0) ? Wq : ((mat == 1) ? Wk : Wv);
  const float* Wb = Wsel + (size_t)(p * 3 + dm) * 4096;
  __half* ob = (mat == 0) ? qh : ((mat == 1) ? kh : vh);
  float wreg[64];
#pragma unroll
  for (int f = 0; f < 64; f++) wreg[f] = Wb[f * 64 + g];
  __syncthreads();
  for (int r = 0; r < 16; r++) {
    float acc = 0.f;
#pragma unroll
    for (int f4 = 0; f4 < 16; f4++) {
      float4 a = *(const float4*)(xt + r * 64 + f4 * 4);  // LDS broadcast
      acc += a.x * wreg[4 * f4] + a.y * wreg[4 * f4 + 1] + a.z * wreg[4 * f4 + 2] +
             a.w * wreg[4 * f4 + 3];
    }
    ob[((size_t)(n0 + r) * 18 + pm) * 64 + g] = __float2half(acc);
  }
}

// ---------------- K4: fp16-LDS eq+ev GEMM via v_dot2_f32_f16 + qk logits ------------
// grid 4500 blocks x 256: 16 slots/block staged coalesced (fp16); wave = 4 slots.
// eq stays in registers; ev written fp16 once. 32 fdot2 per dot (vs 64 v_fma).
__global__ __launch_bounds__(256) void k_edge(const float* __restrict__ fe,
                                              const float* __restrict__ Weqk,
                                              const float* __restrict__ Wev,
                                              const __half* __restrict__ qh,
                                              const __half* __restrict__ kh,
                                              const int* __restrict__ eids,
                                              const int* __restrict__ dsts,
                                              const int* __restrict__ srcs,
                                              __half* __restrict__ evh,
                                              float* __restrict__ logw,
                                              unsigned* __restrict__ lmax) {
  __shared__ __align__(16) __half ft[16 * 576];  // 18 KB fp16
  int s0 = blockIdx.x * 16;
  int g = threadIdx.x & 63;
  int w = threadIdx.x >> 6;
  // weight columns as half2: wqh[j] = (W[2j][g], W[2j+1][g])
  half2_t wqh[32], wvh[32];
#pragma unroll
  for (int j = 0; j < 32; j++) {
    float q0 = Weqk[(size_t)(2 * j) * 64 + g], q1 = Weqk[(size_t)(2 * j + 1) * 64 + g];
    float v0 = Wev[(size_t)(2 * j) * 64 + g], v1 = Wev[(size_t)(2 * j + 1) * 64 + g];
    wqh[j] = half2_t{(_Float16)q0, (_Float16)q1};
    wvh[j] = half2_t{(_Float16)v0, (_Float16)v1};
  }
  {  // coalesced stage + fp32->fp16 convert: 16 threads/slot, 9 float4 each
    int sl = threadIdx.x >> 4, j = threadIdx.x & 15;
    const float* sp = fe + (size_t)eids[s0 + sl] * 576;
#pragma unroll
    for (int i = 0; i < 9; i++) {
      float4 a = *(const float4*)(sp + i * 64 + j * 4);
      __half2 h01 = __floats2half2_rn(a.x, a.y);
      __half2 h23 = __floats2half2_rn(a.z, a.w);
      union { __half2 h[2]; uint2 u; } pk;
      pk.h[0] = h01;
      pk.h[1] = h23;
      *(uint2*)(ft + sl * 576 + i * 64 + j * 4) = pk.u;
    }
  }
  __syncthreads();
  for (int ss = 0; ss < 4; ss++) {
    int sl = w * 4 + ss;
    int s = s0 + sl;
    float eq[9];
#pragma unroll
    for (int m = 0; m < 9; m++) {
      float eqm = 0.f, evm = 0.f;
#pragma unroll
      for (int f8 = 0; f8 < 8; f8++) {
        uint4 hv = *(const uint4*)(ft + sl * 576 + m * 64 + f8 * 8);  // 8 halfs, bcast
        eqm = fdot2f(u2h(hv.x), wqh[f8 * 4 + 0], eqm);
        evm = fdot2f(u2h(hv.x), wvh[f8 * 4 + 0], evm);
        eqm = fdot2f(u2h(hv.y), wqh[f8 * 4 + 1], eqm);
        evm = fdot2f(u2h(hv.y), wvh[f8 * 4 + 1], evm);
        eqm = fdot2f(u2h(hv.z), wqh[f8 * 4 + 2], eqm);
        evm = fdot2f(u2h(hv.z), wvh[f8 * 4 + 2], evm);
        eqm = fdot2f(u2h(hv.w), wqh[f8 * 4 + 3], eqm);
        evm = fdot2f(u2h(hv.w), wvh[f8 * 4 + 3], evm);
      }
      eq[m] = eqm;
      evh[(size_t)s * 576 + m * 64 + g] = __float2half(evm);  // coalesced store
    }
    int dst = __builtin_amdgcn_readfirstlane(dsts[s]);
    int src = __builtin_amdgcn_readfirstlane(srcs[s]);
    const __half* qb = qh + (size_t)dst * 1152 + g;
    const __half* kb = kh + (size_t)src * 1152 + g;
    float lacc = 0.f;
#pragma unroll
    for (int m = 0; m < 9; m++) {
      float qk = __half2float(qb[m * 64]) * __half2float(kb[m * 64]) +
                 __half2float(qb[m * 64 + 576]) * __half2float(kb[m * 64 + 576]);
      lacc += eq[m] * qk;
    }
    lacc *= 0.05892556509887896f;  // 1/sqrt(P*M*DH)=1/sqrt(288)
    lacc += __shfl_xor(lacc, 8, 64);
    lacc += __shfl_xor(lacc, 4, 64);
    lacc += __shfl_xor(lacc, 2, 64);
    lacc += __shfl_xor(lacc, 1, 64);
    if ((g & 15) == 0) {
      int h = g >> 4;
      logw[(size_t)s * 4 + h] = lacc;
      atomicMax(lmax + (size_t)dst * 4 + h, fenc(lacc));
    }
  }
}

// ---------------- K5: w = exp(logit - lmax)*cutoff (slot order), denom sum ----------
__global__ __launch_bounds__(256) void k_expw2(float* __restrict__ logw,
                                               const unsigned* __restrict__ lmax,
                                               const int* __restrict__ dsts,
                                               const float* __restrict__ cuts,
                                               float* __restrict__ denom) {
  int t = blockIdx.x * 256 + threadIdx.x;  // exact E*4
  int s = t >> 2, h = t & 3;
  int dst = dsts[s];
  float wv = expf(logw[t] - fdec(lmax[(size_t)dst * 4 + h])) * cuts[s];
  logw[t] = wv;
  unsafeAtomicAdd(denom + (size_t)dst * 4 + h, wv);
}

// ---------------- K6: CSR gather aggregation, wave per dst, coalesced fp16 ----------
__global__ __launch_bounds__(256) void k_fagg2(const __half* __restrict__ evh,
                                               const __half* __restrict__ vh,
                                               const int* __restrict__ srcs,
                                               const int* __restrict__ rowptr,
                                               const float* __restrict__ logw,
                                               const float* __restrict__ denom,
                                               float* __restrict__ attn_out) {
  int dst = (blockIdx.x * 256 + threadIdx.x) >> 6;  // exact 6000 (1500 blocks)
  int g = threadIdx.x & 63;
  int e0 = __builtin_amdgcn_readfirstlane(rowptr[dst]);
  int e1 = __builtin_amdgcn_readfirstlane(rowptr[dst + 1]);
  float invd = 1.f / (denom[(size_t)dst * 4 + (g >> 4)] + 1e-9f);
  float acc[18];
#pragma unroll
  for (int i = 0; i < 18; i++) acc[i] = 0.f;
  for (int s = e0; s < e1; s++) {
    float attn = logw[(size_t)s * 4 + (g >> 4)] * invd;
    int src = __builtin_amdgcn_readfirstlane(srcs[s]);
    const __half* eb = evh + (size_t)s * 576 + g;
    const __half* vb = vh + (size_t)src * 1152 + g;
#pragma unroll
    for (int m = 0; m < 9; m++) {
      float sc = attn * __half2float(eb[m * 64]);
      acc[m] += sc * __half2float(vb[m * 64]);
      acc[m + 9] += sc * __half2float(vb[m * 64 + 576]);
    }
  }
  float* ob = attn_out + (size_t)dst * 1152 + g;
#pragma unroll
  for (int m = 0; m < 9; m++) {
    ob[m * 64] = acc[m];
    ob[m * 64 + 576] = acc[m + 9];
  }
}

// ---------------- K7: LDS-tiled Wo projection + post-select + gate + residual -------
__global__ __launch_bounds__(256) void k_wo_post3(const float* __restrict__ attn_out,
                                                  const float* __restrict__ Wo,
                                                  const float* __restrict__ xpre,
                                                  const float* __restrict__ fnodes,
                                                  const float* __restrict__ c,
                                                  const float* __restrict__ cnt,
                                                  const float* __restrict__ cutsum,
                                                  float* __restrict__ out) {
  __shared__ __align__(16) float xt[16 * 64];  // 4 KB
  int pm = blockIdx.y;
  int p = pm / 9, dm = deg_of(pm % 9);
  int n0 = blockIdx.x * 16;
  int g = threadIdx.x & 63, w = threadIdx.x >> 6;
  for (int i = threadIdx.x; i < 1024; i += 256) {
    int r = i >> 6, f = i & 63;
    xt[i] = attn_out[((size_t)(n0 + r) * 18 + pm) * 64 + f];
  }
  const float* Wb = Wo + (size_t)(p * 3 + dm) * 4096;
  float wreg[64];
#pragma unroll
  for (int f = 0; f < 64; f++) wreg[f] = Wb[f * 64 + g];
  __syncthreads();
  for (int i = 0; i < 4; i++) {
    int r = w * 4 + i;
    int n = n0 + r;
    float acc = 0.f;
#pragma unroll
    for (int f4 = 0; f4 < 16; f4++) {
      float4 a = *(const float4*)(xt + r * 64 + f4 * 4);
      acc += a.x * wreg[4 * f4] + a.y * wreg[4 * f4 + 1] + a.z * wreg[4 * f4 + 2] +
             a.w * wreg[4 * f4 + 3];
    }
    float mc = cutsum[n] / fmaxf(cnt[n], 1.f);
    size_t idx = ((size_t)n * 18 + pm) * 64 + g;
    float post = (mc < 1e-5f) ? xpre[idx] : acc;
    float a1v = c[(size_t)n * 1664 + 448 + (p * 3 + dm) * 64 + g];
    out[idx] = fnodes[idx] + a1v * post;
  }
}

// ---------------- K9a: h_pre[n][pm][j] = x@W1 (un-gated), (375,18) grid ------------
__global__ __launch_bounds__(256) void k_mlp1v2(const float* __restrict__ xp2,
                                                const float* __restrict__ W1,
                                                float* __restrict__ h) {
  __shared__ __align__(16) float xt[16 * 64];  // 4 KB
  int pm = blockIdx.y;
  int p = pm / 9, dm = deg_of(pm % 9);
  int n0 = blockIdx.x * 16;
  int w = threadIdx.x >> 6, g = threadIdx.x & 63;
  const float* w1b = W1 + (size_t)(p * 3 + dm) * 16384;
  float w1reg[64];
#pragma unroll
  for (int f = 0; f < 64; f++) w1reg[f] = w1b[(size_t)f * 256 + w * 64 + g];
  for (int i = threadIdx.x; i < 1024; i += 256) {
    int r = i >> 6, f = i & 63;
    xt[i] = xp2[((size_t)(n0 + r) * 18 + pm) * 64 + f];
  }
  __syncthreads();
  for (int r = 0; r < 16; r++) {
    float a0 = 0.f, a1 = 0.f, a2 = 0.f, a3 = 0.f;  // 4 chains to hide FMA latency
#pragma unroll
    for (int f4 = 0; f4 < 16; f4 += 4) {
      float4 x0 = *(const float4*)(xt + r * 64 + f4 * 4);
      float4 x1 = *(const float4*)(xt + r * 64 + f4 * 4 + 4);
      float4 x2 = *(const float4*)(xt + r * 64 + f4 * 4 + 8);
      float4 x3 = *(const float4*)(xt + r * 64 + f4 * 4 + 12);
      a0 += x0.x * w1reg[4 * f4] + x0.y * w1reg[4 * f4 + 1] + x0.z * w1reg[4 * f4 + 2] +
            x0.w * w1reg[4 * f4 + 3];
      a1 += x1.x * w1reg[4 * f4 + 4] + x1.y * w1reg[4 * f4 + 5] +
            x1.z * w1reg[4 * f4 + 6] + x1.w * w1reg[4 * f4 + 7];
      a2 += x2.x * w1reg[4 * f4 + 8] + x2.y * w1reg[4 * f4 + 9] +
            x2.z * w1reg[4 * f4 + 10] + x2.w * w1reg[4 * f4 + 11];
      a3 += x3.x * w1reg[4 * f4 + 12] + x3.y * w1reg[4 * f4 + 13] +
            x3.z * w1reg[4 * f4 + 14] + x3.w * w1reg[4 * f4 + 15];
    }
    // coalesced store: h[n][pm][j], j = w*64+g
    h[((size_t)(n0 + r) * 18 + pm) * 256 + w * 64 + g] = (a0 + a1) + (a2 + a3);
  }
}

// ---------------- K9b: gate[n][j] = gelu(s)/s from h_pre[n,pm=0,:], elementwise -----
__global__ __launch_bounds__(256) void k_gate2(const float* __restrict__ h,
                                               float* __restrict__ gatebuf) {
  int n = blockIdx.x;  // 6000 blocks
  int j = threadIdx.x;
  float s = h[(size_t)n * 4608 + j];
  float gt = (fabsf(s) > 1e-4f)
                 ? 0.5f * (1.f + tanhf(0.7978845608028654f * (s + 0.044715f * s * s * s)))
                 : 0.5f;
  gatebuf[(size_t)n * 256 + j] = gt;
}

// ---------------- K9c: out += a2 * ((h_pre*gate) @ W2), (375,18) grid ---------------
__global__ __launch_bounds__(256) void k_mlp2v2(const float* __restrict__ h,
                                                const float* __restrict__ W2,
                                                const float* __restrict__ gatebuf,
                                                const float* __restrict__ c,
                                                float* __restrict__ out) {
  __shared__ __align__(16) float ht[16 * 256];  // 16 KB
  __shared__ float po[4][16 * 64];              // 16 KB
  int pm = blockIdx.y;
  int p = pm / 9, dm = deg_of(pm % 9);
  int n0 = blockIdx.x * 16;
  int w = threadIdx.x >> 6, g = threadIdx.x & 63;
  const float* w2b = W2 + (size_t)(p * 3 + dm) * 16384;
  float w2reg[64];
#pragma unroll
  for (int k = 0; k < 64; k++) w2reg[k] = w2b[(size_t)(w * 64 + k) * 64 + g];
  for (int i = threadIdx.x; i < 4096; i += 256) {  // stage gated h tile, coalesced
    int r = i >> 8, k = i & 255;
    ht[i] = h[((size_t)(n0 + r) * 18 + pm) * 256 + k] *
            gatebuf[(size_t)(n0 + r) * 256 + k];
  }
  __syncthreads();
  for (int r = 0; r < 16; r++) {
    float a0 = 0.f, a1 = 0.f, a2 = 0.f, a3 = 0.f;
#pragma unroll
    for (int k4 = 0; k4 < 16; k4 += 4) {
      float4 h0 = *(const float4*)(ht + r * 256 + w * 64 + k4 * 4);
      float4 h1 = *(const float4*)(ht + r * 256 + w * 64 + k4 * 4 + 4);
      float4 h2 = *(const float4*)(ht + r * 256 + w * 64 + k4 * 4 + 8);
      float4 h3 = *(const float4*)(ht + r * 256 + w * 64 + k4 * 4 + 12);
      a0 += h0.x * w2reg[4 * k4] + h0.y * w2reg[4 * k4 + 1] + h0.z * w2reg[4 * k4 + 2] +
            h0.w * w2reg[4 * k4 + 3];
      a1 += h1.x * w2reg[4 * k4 + 4] + h1.y * w2reg[4 * k4 + 5] +
            h1.z * w2reg[4 * k4 + 6] + h1.w * w2reg[4 * k4 + 7];
      a2 += h2.x * w2reg[4 * k4 + 8] + h2.y * w2reg[4 * k4 + 9] +
            h2.z * w2reg[4 * k4 + 10] + h2.w * w2reg[4 * k4 + 11];
      a3 += h3.x * w2reg[4 * k4 + 12] + h3.y * w2reg[4 * k4 + 13] +
            h3.z * w2reg[4 * k4 + 14] + h3.w * w2reg[4 * k4 + 15];
    }
    po[w][r * 64 + g] = (a0 + a1) + (a2 + a3);
  }
  __syncthreads();
  for (int i = threadIdx.x; i < 1024; i += 256) {
    int r = i >> 6, gg = i & 63;
    float s2 = po[0][i] + po[1][i] + po[2][i] + po[3][i];
    int n = n0 + r;
    size_t idx = ((size_t)n * 18 + pm) * 64 + gg;
    out[idx] += c[(size_t)n * 1664 + 1280 + (p * 3 + dm) * 64 + gg] * s2;
  }
}

// ---------------- workspace layout (bytes) ----------------
#define OFF_C 0UL              // 39,936,000
#define OFF_XPRE 39936000UL    // 27,648,000 (reused as x_pre2)
#define OFF_QH 67584000UL      // 13,824,000 fp16 q
#define OFF_KH 81408000UL      // 13,824,000 fp16 k
#define OFF_VH 95232000UL      // 13,824,000 fp16 v
#define OFF_EVH 109056000UL    // 82,944,000 fp16 ev
#define OFF_ATTN 67584000UL    // 27,648,000 fp32 (over dead q+k after k_edge)
#define OFF_H 67584000UL       // 110,592,000 h_pre (over q,k,v,attn,ev — dead by MLP)
#define OFF_SBUF 192000000UL   // 1,536,000
#define OFF_LOGW 193536000UL   // 1,152,000
#define OFF_LMAX 194688000UL   // 96,000
#define OFF_DENOM 194784000UL  // 96,000
#define OFF_CNT 194880000UL    // 24,000
#define OFF_CUTSUM 194904000UL // 24,000
#define OFF_ROWPTR 194928000UL // 24,064
#define OFF_FILLC 194952064UL  // 24,000
#define OFF_EIDS 194976064UL   // 288,000
#define OFF_DSTS 195264064UL   // 288,000
#define OFF_SRCS 195552064UL   // 288,000
#define OFF_CUTS 195840064UL   // 288,000
#define OFF_GATE 196128064UL   // 6,144,000 (N x 256 fp32 gelu gate)
#define WS_NEEDED 202272064UL

extern "C" void kernel_launch(void* const* d_in, const int* in_sizes, int n_in,
                              void* d_out, int out_size, void* d_ws, size_t ws_size,
                              hipStream_t stream) {
  const float* f_nodes = (const float*)d_in[0];
  const float* f_edges = (const float*)d_in[1];
  const float* f_time = (const float*)d_in[2];
  const float* cutoff = (const float*)d_in[3];
  const float* ln_s = (const float*)d_in[4];
  const float* ln_b = (const float*)d_in[5];
  const float* W_c = (const float*)d_in[6];
  const float* b_c = (const float*)d_in[7];
  const float* Wq = (const float*)d_in[8];
  const float* Wk = (const float*)d_in[9];
  const float* Wv = (const float*)d_in[10];
  const float* Wo = (const float*)d_in[11];
  const float* We_qk = (const float*)d_in[12];
  const float* We_v = (const float*)d_in[13];
  const float* W1 = (const float*)d_in[14];
  const float* W2 = (const float*)d_in[15];
  const int* src_idx = (const int*)d_in[16];
  const int* dst_idx = (const int*)d_in[17];
  float* out = (float*)d_out;
  char* ws = (char*)d_ws;
  if (ws_size < WS_NEEDED) return;  // insufficient scratch; would show as poison absmax

  float* c = (float*)(ws + OFF_C);
  float* xpre = (float*)(ws + OFF_XPRE);
  __half* qh = (__half*)(ws + OFF_QH);
  __half* kh = (__half*)(ws + OFF_KH);
  __half* vh = (__half*)(ws + OFF_VH);
  __half* evh = (__half*)(ws + OFF_EVH);
  float* attn_out = (float*)(ws + OFF_ATTN);
  float* hbuf = (float*)(ws + OFF_H);
  float* sbuf = (float*)(ws + OFF_SBUF);
  float* logw = (float*)(ws + OFF_LOGW);
  unsigned* lmax = (unsigned*)(ws + OFF_LMAX);
  float* denom = (float*)(ws + OFF_DENOM);
  float* cnt = (float*)(ws + OFF_CNT);
  float* cutsum = (float*)(ws + OFF_CUTSUM);
  int* rowptr = (int*)(ws + OFF_ROWPTR);
  int* fillc = (int*)(ws + OFF_FILLC);
  int* eids = (int*)(ws + OFF_EIDS);
  int* dsts = (int*)(ws + OFF_DSTS);
  int* srcs = (int*)(ws + OFF_SRCS);
  float* cuts = (float*)(ws + OFF_CUTS);
  float* gatebuf = (float*)(ws + OFF_GATE);

  // zero lmax/denom/cnt/cutsum (contiguous)
  hipMemsetAsync(ws + OFF_LMAX, 0, 240000, stream);

  k_ln_t<<<1500, 256, 0, stream>>>(f_time, ln_s, ln_b, sbuf);
  k_count<<<282, 256, 0, stream>>>(dst_idx, cutoff, cnt, cutsum);
  k_cond_mm<<<750, 256, 0, stream>>>(sbuf, W_c, b_c, c);
  k_scan<<<1, 1024, 0, stream>>>(cnt, rowptr, fillc);
  k_fill<<<282, 256, 0, stream>>>(dst_idx, src_idx, cutoff, fillc, eids, dsts, srcs,
                                  cuts);
  k_lnmod<<<3000, 256, 0, stream>>>(f_nodes, c, xpre, 0, 384);

  k_qkv2<<<dim3(375, 18), 192, 0, stream>>>(xpre, Wq, Wk, Wv, qh, kh, vh);

  k_edge<<<4500, 256, 0, stream>>>(f_edges, We_qk, We_v, qh, kh, eids, dsts, srcs, evh,
                                   logw, lmax);
  k_expw2<<<1125, 256, 0, stream>>>(logw, lmax, dsts, cuts, denom);
  k_fagg2<<<1500, 256, 0, stream>>>(evh, vh, srcs, rowptr, logw, denom, attn_out);
  k_wo_post3<<<dim3(375, 18), 256, 0, stream>>>(attn_out, Wo, xpre, f_nodes, c, cnt,
                                                cutsum, out);

  k_lnmod<<<3000, 256, 0, stream>>>(out, c, xpre, 832, 1216);  // x_pre2 (buffer reuse)
  k_mlp1v2<<<dim3(375, 18), 256, 0, stream>>>(xpre, W1, hbuf);
  k_gate2<<<6000, 256, 0, stream>>>(hbuf, gatebuf);
  k_mlp2v2<<<dim3(375, 18), 256, 0, stream>>>(hbuf, W2, gatebuf, c, out);
}

// Round 8
// 920.554 us; speedup vs baseline: 1.0922x; 1.0922x over previous
//
#include <hip/hip_runtime.h>
#include <hip/hip_fp16.h>
#include <math.h>

// SO3 DiT layer, MI355X fp32. N=6000, E=72000, P=2, L=2, M=9, F=64, H=4, DH=16
// R3: coalesced LDS staging for edge/proj GEMMs. 1370 -> 1080 us.
// R6: un-fused MLP, lane-coalesced h. 1285 -> 976 us.
// R7: fdot2 halved VALU work; time flat (266 us) -> k_edge is issue/latency
// bound on broadcast LDS reads + dependent accum chains, not VALU throughput.
// R8: MFMA for the edge GEMM (E*M=648k rows x K=64 x N=64, shared 64x64 W).
// One slot = one 16-row MFMA tile (9 real m-rows + 7 pad). 16 mfma_16x16x32_f16
// per slot (eq+ev), D reshaped via per-wave padded LDS tile (stride 68, 2-way
// free) to the proven lane=g layout; qk-dot/ev-store/logits code unchanged.

#define NN 6000
#define EE 72000

typedef _Float16 f16x8 __attribute__((ext_vector_type(8)));
typedef float f32x4 __attribute__((ext_vector_type(4)));

__device__ __forceinline__ float wsum(float v) {
#pragma unroll
  for (int o = 32; o >= 1; o >>= 1) v += __shfl_xor(v, o, 64);
  return v;
}
__device__ __forceinline__ int deg_of(int m) { return (m == 0) ? 0 : ((m < 4) ? 1 : 2); }
// order-preserving float->uint for atomicMax-based segment max
__device__ __forceinline__ unsigned fenc(float x) {
  unsigned u = __float_as_uint(x);
  return (u & 0x80000000u) ? ~u : (u | 0x80000000u);
}
__device__ __forceinline__ float fdec(unsigned k) {
  unsigned u = (k & 0x80000000u) ? (k & 0x7fffffffu) : ~k;
  return __uint_as_float(u);
}

// ---------------- K1a: LayerNorm(T=64) + SiLU, one wave per node ----------------
__global__ __launch_bounds__(256) void k_ln_t(const float* __restrict__ ft,
                                              const float* __restrict__ lns,
                                              const float* __restrict__ lnb,
                                              float* __restrict__ sbuf) {
  int w = (blockIdx.x * 256 + threadIdx.x) >> 6;  // node, exact 6000
  int lane = threadIdx.x & 63;
  float t = ft[(size_t)w * 64 + lane];
  float mu = wsum(t) * (1.f / 64.f);
  float d = t - mu;
  float var = wsum(d * d) * (1.f / 64.f);
  float cin = d * rsqrtf(var + 1e-6f) * lns[lane] + lnb[lane];
  sbuf[(size_t)w * 64 + lane] = cin / (1.f + expf(-cin));
}

// ---------------- K1b: c = silu @ W_c + b_c  (64 -> 1664), 8 nodes/block ----------------
__global__ __launch_bounds__(256) void k_cond_mm(const float* __restrict__ sbuf,
                                                 const float* __restrict__ Wc,
                                                 const float* __restrict__ bc,
                                                 float* __restrict__ c) {
  __shared__ __align__(16) float st[8 * 64];  // 2 KB
  int n0 = blockIdx.x * 8;  // 750 blocks
  for (int i = threadIdx.x; i < 512; i += 256) st[i] = sbuf[(size_t)n0 * 64 + i];
  __syncthreads();
  for (int jj = threadIdx.x; jj < 1664; jj += 256) {
    float acc[8] = {0, 0, 0, 0, 0, 0, 0, 0};
#pragma unroll 8
    for (int k2 = 0; k2 < 64; k2++) {
      float wv = Wc[(size_t)k2 * 1664 + jj];
#pragma unroll
      for (int nd = 0; nd < 8; nd++) acc[nd] += st[nd * 64 + k2] * wv;
    }
    float b = bc[jj];
#pragma unroll
    for (int nd = 0; nd < 8; nd++) c[(size_t)(n0 + nd) * 1664 + jj] = acc[nd] + b;
  }
}

// ---------------- K2/K8: eqv layernorm + modulate, one wave per (n,p) ----------------
__global__ __launch_bounds__(256) void k_lnmod(const float* __restrict__ xin,
                                               const float* __restrict__ c,
                                               float* __restrict__ xout,
                                               int goff, int boff) {
  int w = (blockIdx.x * 256 + threadIdx.x) >> 6;  // (n,p) pair, exact 12000
  int lane = threadIdx.x & 63;
  int n = w >> 1, p = w & 1;
  const float* xb = xin + (size_t)w * 576 + lane;
  float x0 = xb[0], x1 = xb[64], x2 = xb[128], x3 = xb[192], x4 = xb[256];
  float x5 = xb[320], x6 = xb[384], x7 = xb[448], x8 = xb[512];
  float mu = wsum(x0) * (1.f / 64.f);
  x0 -= mu;
  float n20 = x0 * x0;
  float n21 = (x1 * x1 + x2 * x2 + x3 * x3) * (1.f / 3.f);
  float n22 = (x4 * x4 + x5 * x5 + x6 * x6 + x7 * x7 + x8 * x8) * (1.f / 5.f);
  n20 = wsum(n20) * (1.f / 64.f);
  n21 = wsum(n21) * (1.f / 64.f);
  n22 = wsum(n22) * (1.f / 64.f);
  float i0 = rsqrtf(n20 + 1e-6f), i1 = rsqrtf(n21 + 1e-6f), i2 = rsqrtf(n22 + 1e-6f);
  const float* cb = c + (size_t)n * 1664;
  float g0 = 1.f + cb[goff + p * 192 + lane];
  float g1 = 1.f + cb[goff + p * 192 + 64 + lane];
  float g2 = 1.f + cb[goff + p * 192 + 128 + lane];
  float bsh = cb[boff + lane];
  float* ob = xout + (size_t)w * 576 + lane;
  ob[0] = x0 * i0 * g0 + bsh;
  ob[64] = x1 * i1 * g1;
  ob[128] = x2 * i1 * g1;
  ob[192] = x3 * i1 * g1;
  ob[256] = x4 * i2 * g2;
  ob[320] = x5 * i2 * g2;
  ob[384] = x6 * i2 * g2;
  ob[448] = x7 * i2 * g2;
  ob[512] = x8 * i2 * g2;
}

// ---------------- CSR build: count, scan, fill ----------------
__global__ __launch_bounds__(256) void k_count(const int* __restrict__ dst_idx,
                                               const float* __restrict__ cutoff,
                                               float* __restrict__ cnt,
                                               float* __restrict__ cutsum) {
  int e = blockIdx.x * 256 + threadIdx.x;
  if (e >= EE) return;
  int d = dst_idx[e];
  unsafeAtomicAdd(cnt + d, 1.f);
  unsafeAtomicAdd(cutsum + d, cutoff[e]);
}

__global__ __launch_bounds__(1024) void k_scan(const float* __restrict__ cnt,
                                               int* __restrict__ rowptr,
                                               int* __restrict__ fillc) {
  __shared__ int part[1024];
  int t = threadIdx.x;
  int base = t * 6;  // 1024*6 = 6144 >= 6000
  int lc[6];
  int s = 0;
#pragma unroll
  for (int i = 0; i < 6; i++) {
    int idx = base + i;
    int vv = (idx < NN) ? (int)(cnt[idx] + 0.5f) : 0;
    lc[i] = s;
    s += vv;
  }
  part[t] = s;
  __syncthreads();
  for (int o = 1; o < 1024; o <<= 1) {
    int vv = (t >= o) ? part[t - o] : 0;
    __syncthreads();
    part[t] += vv;
    __syncthreads();
  }
  int ex = (t == 0) ? 0 : part[t - 1];
#pragma unroll
  for (int i = 0; i < 6; i++) {
    int idx = base + i;
    if (idx < NN) {
      int p = ex + lc[i];
      rowptr[idx] = p;
      fillc[idx] = p;
    }
  }
  if (t == 1023) rowptr[NN] = part[1023];  // == EE
}

__global__ __launch_bounds__(256) void k_fill(const int* __restrict__ dst_idx,
                                              const int* __restrict__ src_idx,
                                              const float* __restrict__ cutoff,
                                              int* __restrict__ fillc,
                                              int* __restrict__ eids,
                                              int* __restrict__ dsts,
                                              int* __restrict__ srcs,
                                              float* __restrict__ cuts) {
  int e = blockIdx.x * 256 + threadIdx.x;
  if (e >= EE) return;
  int d = dst_idx[e];
  int pos = atomicAdd(fillc + d, 1);
  eids[pos] = e;
  dsts[pos] = d;
  srcs[pos] = src_idx[e];
  cuts[pos] = cutoff[e];
}

// ---------------- K3: fused q/k/v projection, LDS-tiled, fp16 out ----------------
// grid (375, 18), 192 threads: wave = one of {q,k,v}; 16 nodes/block staged once.
__global__ __launch_bounds__(192) void k_qkv2(const float* __restrict__ xpre,
                                              const float* __restrict__ Wq,
                                              const float* __restrict__ Wk,
                                              const float* __restrict__ Wv,
                                              __half* __restrict__ qh,
                                              __half* __restrict__ kh,
                                              __half* __restrict__ vh) {
  __shared__ __align__(16) float xt[16 * 64];  // 4 KB
  int pm = blockIdx.y;
  int p = pm / 9, dm = deg_of(pm % 9);
  int n0 = blockIdx.x * 16;
  int mat = threadIdx.x >> 6;  // wave-uniform: 0=q 1=k 2=v
  int g = threadIdx.x & 63;
  for (int i = threadIdx.x; i < 1024; i += 192) {
    int r = i >> 6, f = i & 63;
    xt[i] = xpre[((size_t)(n0 + r) * 18 + pm) * 64 + f];
  }
  const float* Wsel = (mat == 0) ? Wq : ((mat == 1) ? Wk : Wv);
  const float* Wb = Wsel + (size_t)(p * 3 + dm) * 4096;
  __half* ob = (mat == 0) ? qh : ((mat == 1) ? kh : vh);
  float wreg[64];
#pragma unroll
  for (int f = 0; f < 64; f++) wreg[f] = Wb[f * 64 + g];
  __syncthreads();
  for (int r = 0; r < 16; r++) {
    float acc = 0.f;
#pragma unroll
    for (int f4 = 0; f4 < 16; f4++) {
      float4 a = *(const float4*)(xt + r * 64 + f4 * 4);  // LDS broadcast
      acc += a.x * wreg[4 * f4] + a.y * wreg[4 * f4 + 1] + a.z * wreg[4 * f4 + 2] +
             a.w * wreg[4 * f4 + 3];
    }
    ob[((size_t)(n0 + r) * 18 + pm) * 64 + g] = __float2half(acc);
  }
}

// ---------------- K4: MFMA eq+ev GEMM + qk logits + segment max ----------------
// One slot = one 16-row tile (rows = m, 9 valid + 7 pad). Per wave: 4 slots.
// A: fe rows fp32->fp16 per-lane gather (row=lane&15, k=(lane>>4)*8+j).
// B: W[k][col], col=ct*16+(lane&15). D: col=lane&15, row=(lane>>4)*4+reg.
// D reshaped via per-wave LDS tile [16][68] (2-way bank, free) -> lane=g code.
__global__ __launch_bounds__(256) void k_edge_mfma(const float* __restrict__ fe,
                                                   const float* __restrict__ Weqk,
                                                   const float* __restrict__ Wev,
                                                   const __half* __restrict__ qh,
                                                   const __half* __restrict__ kh,
                                                   const int* __restrict__ eids,
                                                   const int* __restrict__ dsts,
                                                   const int* __restrict__ srcs,
                                                   __half* __restrict__ evh,
                                                   float* __restrict__ logw,
                                                   unsigned* __restrict__ lmax) {
  __shared__ float ldsbuf[4 * 2176];  // per wave: eq[16][68] + ev[16][68], 34.8 KB
  int lane = threadIdx.x & 63;
  int wid = threadIdx.x >> 6;
  int r16 = lane & 15;  // A-row (m) / B,D col-within-tile
  int kg = lane >> 4;   // k-group
  // B fragments (loaded once): [mat][ct][ks], k = ks*32 + kg*8 + j
  f16x8 bfrag[2][4][2];
#pragma unroll
  for (int ct = 0; ct < 4; ct++) {
#pragma unroll
    for (int ks = 0; ks < 2; ks++) {
      f16x8 bq, bv;
#pragma unroll
      for (int j = 0; j < 8; j++) {
        int k = ks * 32 + kg * 8 + j;
        bq[j] = (_Float16)Weqk[(size_t)k * 64 + ct * 16 + r16];
        bv[j] = (_Float16)Wev[(size_t)k * 64 + ct * 16 + r16];
      }
      bfrag[0][ct][ks] = bq;
      bfrag[1][ct][ks] = bv;
    }
  }
  float* lq = ldsbuf + wid * 2176;
  float* lv = ldsbuf + wid * 2176 + 1088;
  int mclamp = (r16 < 9) ? r16 : 8;  // pad rows recompute row 8, outputs ignored
  int s0 = (blockIdx.x * 4 + wid) * 4;  // 4500 blocks x 4 waves x 4 slots = 72000
  for (int ss = 0; ss < 4; ss++) {
    int s = s0 + ss;
    int e = __builtin_amdgcn_readfirstlane(eids[s]);
    const float* feb = fe + (size_t)e * 576 + mclamp * 64 + kg * 8;
    f16x8 a0, a1;
    {
      float4 p0 = *(const float4*)(feb);
      float4 p1 = *(const float4*)(feb + 4);
      float4 p2 = *(const float4*)(feb + 32);
      float4 p3 = *(const float4*)(feb + 36);
      a0[0] = (_Float16)p0.x; a0[1] = (_Float16)p0.y;
      a0[2] = (_Float16)p0.z; a0[3] = (_Float16)p0.w;
      a0[4] = (_Float16)p1.x; a0[5] = (_Float16)p1.y;
      a0[6] = (_Float16)p1.z; a0[7] = (_Float16)p1.w;
      a1[0] = (_Float16)p2.x; a1[1] = (_Float16)p2.y;
      a1[2] = (_Float16)p2.z; a1[3] = (_Float16)p2.w;
      a1[4] = (_Float16)p3.x; a1[5] = (_Float16)p3.y;
      a1[6] = (_Float16)p3.z; a1[7] = (_Float16)p3.w;
    }
#pragma unroll
    for (int ct = 0; ct < 4; ct++) {
      f32x4 zq = {0.f, 0.f, 0.f, 0.f};
      zq = __builtin_amdgcn_mfma_f32_16x16x32_f16(a0, bfrag[0][ct][0], zq, 0, 0, 0);
      zq = __builtin_amdgcn_mfma_f32_16x16x32_f16(a1, bfrag[0][ct][1], zq, 0, 0, 0);
      f32x4 zv = {0.f, 0.f, 0.f, 0.f};
      zv = __builtin_amdgcn_mfma_f32_16x16x32_f16(a0, bfrag[1][ct][0], zv, 0, 0, 0);
      zv = __builtin_amdgcn_mfma_f32_16x16x32_f16(a1, bfrag[1][ct][1], zv, 0, 0, 0);
      // D: row = kg*4 + reg, col = ct*16 + r16
#pragma unroll
      for (int reg = 0; reg < 4; reg++) {
        lq[(kg * 4 + reg) * 68 + ct * 16 + r16] = zq[reg];
        lv[(kg * 4 + reg) * 68 + ct * 16 + r16] = zv[reg];
      }
    }
    // same-wave LDS RAW: compiler inserts lgkmcnt wait
    int g = lane;
    int dst = __builtin_amdgcn_readfirstlane(dsts[s]);
    int src = __builtin_amdgcn_readfirstlane(srcs[s]);
    const __half* qb = qh + (size_t)dst * 1152 + g;
    const __half* kb = kh + (size_t)src * 1152 + g;
    float lacc = 0.f;
#pragma unroll
    for (int m = 0; m < 9; m++) {
      float eqv = lq[m * 68 + g];
      evh[(size_t)s * 576 + m * 64 + g] = __float2half(lv[m * 68 + g]);
      float qk = __half2float(qb[m * 64]) * __half2float(kb[m * 64]) +
                 __half2float(qb[m * 64 + 576]) * __half2float(kb[m * 64 + 576]);
      lacc += eqv * qk;
    }
    lacc *= 0.05892556509887896f;  // 1/sqrt(P*M*DH)=1/sqrt(288)
    lacc += __shfl_xor(lacc, 8, 64);
    lacc += __shfl_xor(lacc, 4, 64);
    lacc += __shfl_xor(lacc, 2, 64);
    lacc += __shfl_xor(lacc, 1, 64);
    if ((g & 15) == 0) {
      int h = g >> 4;
      logw[(size_t)s * 4 + h] = lacc;
      atomicMax(lmax + (size_t)dst * 4 + h, fenc(lacc));
    }
  }
}

// ---------------- K5: w = exp(logit - lmax)*cutoff (slot order), denom sum ----------
__global__ __launch_bounds__(256) void k_expw2(float* __restrict__ logw,
                                               const unsigned* __restrict__ lmax,
                                               const int* __restrict__ dsts,
                                               const float* __restrict__ cuts,
                                               float* __restrict__ denom) {
  int t = blockIdx.x * 256 + threadIdx.x;  // exact E*4
  int s = t >> 2, h = t & 3;
  int dst = dsts[s];
  float wv = expf(logw[t] - fdec(lmax[(size_t)dst * 4 + h])) * cuts[s];
  logw[t] = wv;
  unsafeAtomicAdd(denom + (size_t)dst * 4 + h, wv);
}

// ---------------- K6: CSR gather aggregation, wave per dst, coalesced fp16 ----------
__global__ __launch_bounds__(256) void k_fagg2(const __half* __restrict__ evh,
                                               const __half* __restrict__ vh,
                                               const int* __restrict__ srcs,
                                               const int* __restrict__ rowptr,
                                               const float* __restrict__ logw,
                                               const float* __restrict__ denom,
                                               float* __restrict__ attn_out) {
  int dst = (blockIdx.x * 256 + threadIdx.x) >> 6;  // exact 6000 (1500 blocks)
  int g = threadIdx.x & 63;
  int e0 = __builtin_amdgcn_readfirstlane(rowptr[dst]);
  int e1 = __builtin_amdgcn_readfirstlane(rowptr[dst + 1]);
  float invd = 1.f / (denom[(size_t)dst * 4 + (g >> 4)] + 1e-9f);
  float acc[18];
#pragma unroll
  for (int i = 0; i < 18; i++) acc[i] = 0.f;
  for (int s = e0; s < e1; s++) {
    float attn = logw[(size_t)s * 4 + (g >> 4)] * invd;
    int src = __builtin_amdgcn_readfirstlane(srcs[s]);
    const __half* eb = evh + (size_t)s * 576 + g;
    const __half* vb = vh + (size_t)src * 1152 + g;
#pragma unroll
    for (int m = 0; m < 9; m++) {
      float sc = attn * __half2float(eb[m * 64]);
      acc[m] += sc * __half2float(vb[m * 64]);
      acc[m + 9] += sc * __half2float(vb[m * 64 + 576]);
    }
  }
  float* ob = attn_out + (size_t)dst * 1152 + g;
#pragma unroll
  for (int m = 0; m < 9; m++) {
    ob[m * 64] = acc[m];
    ob[m * 64 + 576] = acc[m + 9];
  }
}

// ---------------- K7: LDS-tiled Wo projection + post-select + gate + residual -------
__global__ __launch_bounds__(256) void k_wo_post3(const float* __restrict__ attn_out,
                                                  const float* __restrict__ Wo,
                                                  const float* __restrict__ xpre,
                                                  const float* __restrict__ fnodes,
                                                  const float* __restrict__ c,
                                                  const float* __restrict__ cnt,
                                                  const float* __restrict__ cutsum,
                                                  float* __restrict__ out) {
  __shared__ __align__(16) float xt[16 * 64];  // 4 KB
  int pm = blockIdx.y;
  int p = pm / 9, dm = deg_of(pm % 9);
  int n0 = blockIdx.x * 16;
  int g = threadIdx.x & 63, w = threadIdx.x >> 6;
  for (int i = threadIdx.x; i < 1024; i += 256) {
    int r = i >> 6, f = i & 63;
    xt[i] = attn_out[((size_t)(n0 + r) * 18 + pm) * 64 + f];
  }
  const float* Wb = Wo + (size_t)(p * 3 + dm) * 4096;
  float wreg[64];
#pragma unroll
  for (int f = 0; f < 64; f++) wreg[f] = Wb[f * 64 + g];
  __syncthreads();
  for (int i = 0; i < 4; i++) {
    int r = w * 4 + i;
    int n = n0 + r;
    float acc = 0.f;
#pragma unroll
    for (int f4 = 0; f4 < 16; f4++) {
      float4 a = *(const float4*)(xt + r * 64 + f4 * 4);
      acc += a.x * wreg[4 * f4] + a.y * wreg[4 * f4 + 1] + a.z * wreg[4 * f4 + 2] +
             a.w * wreg[4 * f4 + 3];
    }
    float mc = cutsum[n] / fmaxf(cnt[n], 1.f);
    size_t idx = ((size_t)n * 18 + pm) * 64 + g;
    float post = (mc < 1e-5f) ? xpre[idx] : acc;
    float a1v = c[(size_t)n * 1664 + 448 + (p * 3 + dm) * 64 + g];
    out[idx] = fnodes[idx] + a1v * post;
  }
}

// ---------------- K9a: h_pre[n][pm][j] = x@W1 (un-gated), (375,18) grid ------------
__global__ __launch_bounds__(256) void k_mlp1v2(const float* __restrict__ xp2,
                                                const float* __restrict__ W1,
                                                float* __restrict__ h) {
  __shared__ __align__(16) float xt[16 * 64];  // 4 KB
  int pm = blockIdx.y;
  int p = pm / 9, dm = deg_of(pm % 9);
  int n0 = blockIdx.x * 16;
  int w = threadIdx.x >> 6, g = threadIdx.x & 63;
  const float* w1b = W1 + (size_t)(p * 3 + dm) * 16384;
  float w1reg[64];
#pragma unroll
  for (int f = 0; f < 64; f++) w1reg[f] = w1b[(size_t)f * 256 + w * 64 + g];
  for (int i = threadIdx.x; i < 1024; i += 256) {
    int r = i >> 6, f = i & 63;
    xt[i] = xp2[((size_t)(n0 + r) * 18 + pm) * 64 + f];
  }
  __syncthreads();
  for (int r = 0; r < 16; r++) {
    float a0 = 0.f, a1 = 0.f, a2 = 0.f, a3 = 0.f;  // 4 chains to hide FMA latency
#pragma unroll
    for (int f4 = 0; f4 < 16; f4 += 4) {
      float4 x0 = *(const float4*)(xt + r * 64 + f4 * 4);
      float4 x1 = *(const float4*)(xt + r * 64 + f4 * 4 + 4);
      float4 x2 = *(const float4*)(xt + r * 64 + f4 * 4 + 8);
      float4 x3 = *(const float4*)(xt + r * 64 + f4 * 4 + 12);
      a0 += x0.x * w1reg[4 * f4] + x0.y * w1reg[4 * f4 + 1] + x0.z * w1reg[4 * f4 + 2] +
            x0.w * w1reg[4 * f4 + 3];
      a1 += x1.x * w1reg[4 * f4 + 4] + x1.y * w1reg[4 * f4 + 5] +
            x1.z * w1reg[4 * f4 + 6] + x1.w * w1reg[4 * f4 + 7];
      a2 += x2.x * w1reg[4 * f4 + 8] + x2.y * w1reg[4 * f4 + 9] +
            x2.z * w1reg[4 * f4 + 10] + x2.w * w1reg[4 * f4 + 11];
      a3 += x3.x * w1reg[4 * f4 + 12] + x3.y * w1reg[4 * f4 + 13] +
            x3.z * w1reg[4 * f4 + 14] + x3.w * w1reg[4 * f4 + 15];
    }
    // coalesced store: h[n][pm][j], j = w*64+g
    h[((size_t)(n0 + r) * 18 + pm) * 256 + w * 64 + g] = (a0 + a1) + (a2 + a3);
  }
}

// ---------------- K9b: gate[n][j] = gelu(s)/s from h_pre[n,pm=0,:], elementwise -----
__global__ __launch_bounds__(256) void k_gate2(const float* __restrict__ h,
                                               float* __restrict__ gatebuf) {
  int n = blockIdx.x;  // 6000 blocks
  int j = threadIdx.x;
  float s = h[(size_t)n * 4608 + j];
  float gt = (fabsf(s) > 1e-4f)
                 ? 0.5f * (1.f + tanhf(0.7978845608028654f * (s + 0.044715f * s * s * s)))
                 : 0.5f;
  gatebuf[(size_t)n * 256 + j] = gt;
}

// ---------------- K9c: out += a2 * ((h_pre*gate) @ W2), (375,18) grid ---------------
__global__ __launch_bounds__(256) void k_mlp2v2(const float* __restrict__ h,
                                                const float* __restrict__ W2,
                                                const float* __restrict__ gatebuf,
                                                const float* __restrict__ c,
                                                float* __restrict__ out) {
  __shared__ __align__(16) float ht[16 * 256];  // 16 KB
  __shared__ float po[4][16 * 64];              // 16 KB
  int pm = blockIdx.y;
  int p = pm / 9, dm = deg_of(pm % 9);
  int n0 = blockIdx.x * 16;
  int w = threadIdx.x >> 6, g = threadIdx.x & 63;
  const float* w2b = W2 + (size_t)(p * 3 + dm) * 16384;
  float w2reg[64];
#pragma unroll
  for (int k = 0; k < 64; k++) w2reg[k] = w2b[(size_t)(w * 64 + k) * 64 + g];
  for (int i = threadIdx.x; i < 4096; i += 256) {  // stage gated h tile, coalesced
    int r = i >> 8, k = i & 255;
    ht[i] = h[((size_t)(n0 + r) * 18 + pm) * 256 + k] *
            gatebuf[(size_t)(n0 + r) * 256 + k];
  }
  __syncthreads();
  for (int r = 0; r < 16; r++) {
    float a0 = 0.f, a1 = 0.f, a2 = 0.f, a3 = 0.f;
#pragma unroll
    for (int k4 = 0; k4 < 16; k4 += 4) {
      float4 h0 = *(const float4*)(ht + r * 256 + w * 64 + k4 * 4);
      float4 h1 = *(const float4*)(ht + r * 256 + w * 64 + k4 * 4 + 4);
      float4 h2 = *(const float4*)(ht + r * 256 + w * 64 + k4 * 4 + 8);
      float4 h3 = *(const float4*)(ht + r * 256 + w * 64 + k4 * 4 + 12);
      a0 += h0.x * w2reg[4 * k4] + h0.y * w2reg[4 * k4 + 1] + h0.z * w2reg[4 * k4 + 2] +
            h0.w * w2reg[4 * k4 + 3];
      a1 += h1.x * w2reg[4 * k4 + 4] + h1.y * w2reg[4 * k4 + 5] +
            h1.z * w2reg[4 * k4 + 6] + h1.w * w2reg[4 * k4 + 7];
      a2 += h2.x * w2reg[4 * k4 + 8] + h2.y * w2reg[4 * k4 + 9] +
            h2.z * w2reg[4 * k4 + 10] + h2.w * w2reg[4 * k4 + 11];
      a3 += h3.x * w2reg[4 * k4 + 12] + h3.y * w2reg[4 * k4 + 13] +
            h3.z * w2reg[4 * k4 + 14] + h3.w * w2reg[4 * k4 + 15];
    }
    po[w][r * 64 + g] = (a0 + a1) + (a2 + a3);
  }
  __syncthreads();
  for (int i = threadIdx.x; i < 1024; i += 256) {
    int r = i >> 6, gg = i & 63;
    float s2 = po[0][i] + po[1][i] + po[2][i] + po[3][i];
    int n = n0 + r;
    size_t idx = ((size_t)n * 18 + pm) * 64 + gg;
    out[idx] += c[(size_t)n * 1664 + 1280 + (p * 3 + dm) * 64 + gg] * s2;
  }
}

// ---------------- workspace layout (bytes) ----------------
#define OFF_C 0UL              // 39,936,000
#define OFF_XPRE 39936000UL    // 27,648,000 (reused as x_pre2)
#define OFF_QH 67584000UL      // 13,824,000 fp16 q
#define OFF_KH 81408000UL      // 13,824,000 fp16 k
#define OFF_VH 95232000UL      // 13,824,000 fp16 v
#define OFF_EVH 109056000UL    // 82,944,000 fp16 ev
#define OFF_ATTN 67584000UL    // 27,648,000 fp32 (over dead q+k after k_edge)
#define OFF_H 67584000UL       // 110,592,000 h_pre (over q,k,v,attn,ev — dead by MLP)
#define OFF_SBUF 192000000UL   // 1,536,000
#define OFF_LOGW 193536000UL   // 1,152,000
#define OFF_LMAX 194688000UL   // 96,000
#define OFF_DENOM 194784000UL  // 96,000
#define OFF_CNT 194880000UL    // 24,000
#define OFF_CUTSUM 194904000UL // 24,000
#define OFF_ROWPTR 194928000UL // 24,064
#define OFF_FILLC 194952064UL  // 24,000
#define OFF_EIDS 194976064UL   // 288,000
#define OFF_DSTS 195264064UL   // 288,000
#define OFF_SRCS 195552064UL   // 288,000
#define OFF_CUTS 195840064UL   // 288,000
#define OFF_GATE 196128064UL   // 6,144,000 (N x 256 fp32 gelu gate)
#define WS_NEEDED 202272064UL

extern "C" void kernel_launch(void* const* d_in, const int* in_sizes, int n_in,
                              void* d_out, int out_size, void* d_ws, size_t ws_size,
                              hipStream_t stream) {
  const float* f_nodes = (const float*)d_in[0];
  const float* f_edges = (const float*)d_in[1];
  const float* f_time = (const float*)d_in[2];
  const float* cutoff = (const float*)d_in[3];
  const float* ln_s = (const float*)d_in[4];
  const float* ln_b = (const float*)d_in[5];
  const float* W_c = (const float*)d_in[6];
  const float* b_c = (const float*)d_in[7];
  const float* Wq = (const float*)d_in[8];
  const float* Wk = (const float*)d_in[9];
  const float* Wv = (const float*)d_in[10];
  const float* Wo = (const float*)d_in[11];
  const float* We_qk = (const float*)d_in[12];
  const float* We_v = (const float*)d_in[13];
  const float* W1 = (const float*)d_in[14];
  const float* W2 = (const float*)d_in[15];
  const int* src_idx = (const int*)d_in[16];
  const int* dst_idx = (const int*)d_in[17];
  float* out = (float*)d_out;
  char* ws = (char*)d_ws;
  if (ws_size < WS_NEEDED) return;  // insufficient scratch; would show as poison absmax

  float* c = (float*)(ws + OFF_C);
  float* xpre = (float*)(ws + OFF_XPRE);
  __half* qh = (__half*)(ws + OFF_QH);
  __half* kh = (__half*)(ws + OFF_KH);
  __half* vh = (__half*)(ws + OFF_VH);
  __half* evh = (__half*)(ws + OFF_EVH);
  float* attn_out = (float*)(ws + OFF_ATTN);
  float* hbuf = (float*)(ws + OFF_H);
  float* sbuf = (float*)(ws + OFF_SBUF);
  float* logw = (float*)(ws + OFF_LOGW);
  unsigned* lmax = (unsigned*)(ws + OFF_LMAX);
  float* denom = (float*)(ws + OFF_DENOM);
  float* cnt = (float*)(ws + OFF_CNT);
  float* cutsum = (float*)(ws + OFF_CUTSUM);
  int* rowptr = (int*)(ws + OFF_ROWPTR);
  int* fillc = (int*)(ws + OFF_FILLC);
  int* eids = (int*)(ws + OFF_EIDS);
  int* dsts = (int*)(ws + OFF_DSTS);
  int* srcs = (int*)(ws + OFF_SRCS);
  float* cuts = (float*)(ws + OFF_CUTS);
  float* gatebuf = (float*)(ws + OFF_GATE);

  // zero lmax/denom/cnt/cutsum (contiguous)
  hipMemsetAsync(ws + OFF_LMAX, 0, 240000, stream);

  k_ln_t<<<1500, 256, 0, stream>>>(f_time, ln_s, ln_b, sbuf);
  k_count<<<282, 256, 0, stream>>>(dst_idx, cutoff, cnt, cutsum);
  k_cond_mm<<<750, 256, 0, stream>>>(sbuf, W_c, b_c, c);
  k_scan<<<1, 1024, 0, stream>>>(cnt, rowptr, fillc);
  k_fill<<<282, 256, 0, stream>>>(dst_idx, src_idx, cutoff, fillc, eids, dsts, srcs,
                                  cuts);
  k_lnmod<<<3000, 256, 0, stream>>>(f_nodes, c, xpre, 0, 384);

  k_qkv2<<<dim3(375, 18), 192, 0, stream>>>(xpre, Wq, Wk, Wv, qh, kh, vh);

  k_edge_mfma<<<4500, 256, 0, stream>>>(f_edges, We_qk, We_v, qh, kh, eids, dsts, srcs,
                                        evh, logw, lmax);
  k_expw2<<<1125, 256, 0, stream>>>(logw, lmax, dsts, cuts, denom);
  k_fagg2<<<1500, 256, 0, stream>>>(evh, vh, srcs, rowptr, logw, denom, attn_out);
  k_wo_post3<<<dim3(375, 18), 256, 0, stream>>>(attn_out, Wo, xpre, f_nodes, c, cnt,
                                                cutsum, out);

  k_lnmod<<<3000, 256, 0, stream>>>(out, c, xpre, 832, 1216);  // x_pre2 (buffer reuse)
  k_mlp1v2<<<dim3(375, 18), 256, 0, stream>>>(xpre, W1, hbuf);
  k_gate2<<<6000, 256, 0, stream>>>(hbuf, gatebuf);
  k_mlp2v2<<<dim3(375, 18), 256, 0, stream>>>(hbuf, W2, gatebuf, c, out);
}

// Round 9
// 881.048 us; speedup vs baseline: 1.1412x; 1.0448x over previous
//
#include <hip/hip_runtime.h>
#include <hip/hip_fp16.h>
#include <math.h>

// SO3 DiT layer, MI355X fp32. N=6000, E=72000, P=2, L=2, M=9, F=64, H=4, DH=16
// R3: coalesced LDS staging for edge/proj GEMMs. 1370 -> 1080 us.
// R6: un-fused MLP, lane-coalesced h. 1285 -> 976 us.
// R8: MFMA edge GEMM (16-row tile per slot, D via padded LDS). 1005 -> 920 us;
// k_edge 266 -> 186 us but ALL pipes idle (Mfma 4%, VALU 10%, HBM 18%) ->
// pure exposed latency: serial per-slot chain with one HBM round trip each.
// R9: batch-prefetch all 4 slots' A-tiles + metadata in a prologue (one HBM
// latency window for 4 slots, fragments persist in 32 VGPRs); loop body has
// no A latency, q/k gathers (L2-resident) overlap MFMA+LDS via scheduler.

#define NN 6000
#define EE 72000

typedef _Float16 f16x8 __attribute__((ext_vector_type(8)));
typedef float f32x4 __attribute__((ext_vector_type(4)));

__device__ __forceinline__ float wsum(float v) {
#pragma unroll
  for (int o = 32; o >= 1; o >>= 1) v += __shfl_xor(v, o, 64);
  return v;
}
__device__ __forceinline__ int deg_of(int m) { return (m == 0) ? 0 : ((m < 4) ? 1 : 2); }
// order-preserving float->uint for atomicMax-based segment max
__device__ __forceinline__ unsigned fenc(float x) {
  unsigned u = __float_as_uint(x);
  return (u & 0x80000000u) ? ~u : (u | 0x80000000u);
}
__device__ __forceinline__ float fdec(unsigned k) {
  unsigned u = (k & 0x80000000u) ? (k & 0x7fffffffu) : ~k;
  return __uint_as_float(u);
}
__device__ __forceinline__ f16x8 cvt8(float4 p0, float4 p1) {
  f16x8 a;
  a[0] = (_Float16)p0.x; a[1] = (_Float16)p0.y;
  a[2] = (_Float16)p0.z; a[3] = (_Float16)p0.w;
  a[4] = (_Float16)p1.x; a[5] = (_Float16)p1.y;
  a[6] = (_Float16)p1.z; a[7] = (_Float16)p1.w;
  return a;
}

// ---------------- K1a: LayerNorm(T=64) + SiLU, one wave per node ----------------
__global__ __launch_bounds__(256) void k_ln_t(const float* __restrict__ ft,
                                              const float* __restrict__ lns,
                                              const float* __restrict__ lnb,
                                              float* __restrict__ sbuf) {
  int w = (blockIdx.x * 256 + threadIdx.x) >> 6;  // node, exact 6000
  int lane = threadIdx.x & 63;
  float t = ft[(size_t)w * 64 + lane];
  float mu = wsum(t) * (1.f / 64.f);
  float d = t - mu;
  float var = wsum(d * d) * (1.f / 64.f);
  float cin = d * rsqrtf(var + 1e-6f) * lns[lane] + lnb[lane];
  sbuf[(size_t)w * 64 + lane] = cin / (1.f + expf(-cin));
}

// ---------------- K1b: c = silu @ W_c + b_c  (64 -> 1664), 8 nodes/block ----------------
__global__ __launch_bounds__(256) void k_cond_mm(const float* __restrict__ sbuf,
                                                 const float* __restrict__ Wc,
                                                 const float* __restrict__ bc,
                                                 float* __restrict__ c) {
  __shared__ __align__(16) float st[8 * 64];  // 2 KB
  int n0 = blockIdx.x * 8;  // 750 blocks
  for (int i = threadIdx.x; i < 512; i += 256) st[i] = sbuf[(size_t)n0 * 64 + i];
  __syncthreads();
  for (int jj = threadIdx.x; jj < 1664; jj += 256) {
    float acc[8] = {0, 0, 0, 0, 0, 0, 0, 0};
#pragma unroll 8
    for (int k2 = 0; k2 < 64; k2++) {
      float wv = Wc[(size_t)k2 * 1664 + jj];
#pragma unroll
      for (int nd = 0; nd < 8; nd++) acc[nd] += st[nd * 64 + k2] * wv;
    }
    float b = bc[jj];
#pragma unroll
    for (int nd = 0; nd < 8; nd++) c[(size_t)(n0 + nd) * 1664 + jj] = acc[nd] + b;
  }
}

// ---------------- K2/K8: eqv layernorm + modulate, one wave per (n,p) ----------------
__global__ __launch_bounds__(256) void k_lnmod(const float* __restrict__ xin,
                                               const float* __restrict__ c,
                                               float* __restrict__ xout,
                                               int goff, int boff) {
  int w = (blockIdx.x * 256 + threadIdx.x) >> 6;  // (n,p) pair, exact 12000
  int lane = threadIdx.x & 63;
  int n = w >> 1, p = w & 1;
  const float* xb = xin + (size_t)w * 576 + lane;
  float x0 = xb[0], x1 = xb[64], x2 = xb[128], x3 = xb[192], x4 = xb[256];
  float x5 = xb[320], x6 = xb[384], x7 = xb[448], x8 = xb[512];
  float mu = wsum(x0) * (1.f / 64.f);
  x0 -= mu;
  float n20 = x0 * x0;
  float n21 = (x1 * x1 + x2 * x2 + x3 * x3) * (1.f / 3.f);
  float n22 = (x4 * x4 + x5 * x5 + x6 * x6 + x7 * x7 + x8 * x8) * (1.f / 5.f);
  n20 = wsum(n20) * (1.f / 64.f);
  n21 = wsum(n21) * (1.f / 64.f);
  n22 = wsum(n22) * (1.f / 64.f);
  float i0 = rsqrtf(n20 + 1e-6f), i1 = rsqrtf(n21 + 1e-6f), i2 = rsqrtf(n22 + 1e-6f);
  const float* cb = c + (size_t)n * 1664;
  float g0 = 1.f + cb[goff + p * 192 + lane];
  float g1 = 1.f + cb[goff + p * 192 + 64 + lane];
  float g2 = 1.f + cb[goff + p * 192 + 128 + lane];
  float bsh = cb[boff + lane];
  float* ob = xout + (size_t)w * 576 + lane;
  ob[0] = x0 * i0 * g0 + bsh;
  ob[64] = x1 * i1 * g1;
  ob[128] = x2 * i1 * g1;
  ob[192] = x3 * i1 * g1;
  ob[256] = x4 * i2 * g2;
  ob[320] = x5 * i2 * g2;
  ob[384] = x6 * i2 * g2;
  ob[448] = x7 * i2 * g2;
  ob[512] = x8 * i2 * g2;
}

// ---------------- CSR build: count, scan, fill ----------------
__global__ __launch_bounds__(256) void k_count(const int* __restrict__ dst_idx,
                                               const float* __restrict__ cutoff,
                                               float* __restrict__ cnt,
                                               float* __restrict__ cutsum) {
  int e = blockIdx.x * 256 + threadIdx.x;
  if (e >= EE) return;
  int d = dst_idx[e];
  unsafeAtomicAdd(cnt + d, 1.f);
  unsafeAtomicAdd(cutsum + d, cutoff[e]);
}

__global__ __launch_bounds__(1024) void k_scan(const float* __restrict__ cnt,
                                               int* __restrict__ rowptr,
                                               int* __restrict__ fillc) {
  __shared__ int part[1024];
  int t = threadIdx.x;
  int base = t * 6;  // 1024*6 = 6144 >= 6000
  int lc[6];
  int s = 0;
#pragma unroll
  for (int i = 0; i < 6; i++) {
    int idx = base + i;
    int vv = (idx < NN) ? (int)(cnt[idx] + 0.5f) : 0;
    lc[i] = s;
    s += vv;
  }
  part[t] = s;
  __syncthreads();
  for (int o = 1; o < 1024; o <<= 1) {
    int vv = (t >= o) ? part[t - o] : 0;
    __syncthreads();
    part[t] += vv;
    __syncthreads();
  }
  int ex = (t == 0) ? 0 : part[t - 1];
#pragma unroll
  for (int i = 0; i < 6; i++) {
    int idx = base + i;
    if (idx < NN) {
      int p = ex + lc[i];
      rowptr[idx] = p;
      fillc[idx] = p;
    }
  }
  if (t == 1023) rowptr[NN] = part[1023];  // == EE
}

__global__ __launch_bounds__(256) void k_fill(const int* __restrict__ dst_idx,
                                              const int* __restrict__ src_idx,
                                              const float* __restrict__ cutoff,
                                              int* __restrict__ fillc,
                                              int* __restrict__ eids,
                                              int* __restrict__ dsts,
                                              int* __restrict__ srcs,
                                              float* __restrict__ cuts) {
  int e = blockIdx.x * 256 + threadIdx.x;
  if (e >= EE) return;
  int d = dst_idx[e];
  int pos = atomicAdd(fillc + d, 1);
  eids[pos] = e;
  dsts[pos] = d;
  srcs[pos] = src_idx[e];
  cuts[pos] = cutoff[e];
}

// ---------------- K3: fused q/k/v projection, LDS-tiled, fp16 out ----------------
// grid (375, 18), 192 threads: wave = one of {q,k,v}; 16 nodes/block staged once.
__global__ __launch_bounds__(192) void k_qkv2(const float* __restrict__ xpre,
                                              const float* __restrict__ Wq,
                                              const float* __restrict__ Wk,
                                              const float* __restrict__ Wv,
                                              __half* __restrict__ qh,
                                              __half* __restrict__ kh,
                                              __half* __restrict__ vh) {
  __shared__ __align__(16) float xt[16 * 64];  // 4 KB
  int pm = blockIdx.y;
  int p = pm / 9, dm = deg_of(pm % 9);
  int n0 = blockIdx.x * 16;
  int mat = threadIdx.x >> 6;  // wave-uniform: 0=q 1=k 2=v
  int g = threadIdx.x & 63;
  for (int i = threadIdx.x; i < 1024; i += 192) {
    int r = i >> 6, f = i & 63;
    xt[i] = xpre[((size_t)(n0 + r) * 18 + pm) * 64 + f];
  }
  const float* Wsel = (mat == 0) ? Wq : ((mat == 1) ? Wk : Wv);
  const float* Wb = Wsel + (size_t)(p * 3 + dm) * 4096;
  __half* ob = (mat == 0) ? qh : ((mat == 1) ? kh : vh);
  float wreg[64];
#pragma unroll
  for (int f = 0; f < 64; f++) wreg[f] = Wb[f * 64 + g];
  __syncthreads();
  for (int r = 0; r < 16; r++) {
    float acc = 0.f;
#pragma unroll
    for (int f4 = 0; f4 < 16; f4++) {
      float4 a = *(const float4*)(xt + r * 64 + f4 * 4);  // LDS broadcast
      acc += a.x * wreg[4 * f4] + a.y * wreg[4 * f4 + 1] + a.z * wreg[4 * f4 + 2] +
             a.w * wreg[4 * f4 + 3];
    }
    ob[((size_t)(n0 + r) * 18 + pm) * 64 + g] = __float2half(acc);
  }
}

// ---------------- K4: MFMA eq+ev GEMM + qk logits, 4-slot A prefetch ----------------
// One slot = one 16-row tile (rows = m, 9 valid + 7 pad clamped to row 8).
// Prologue: eids/dsts/srcs + all 4 slots' A tiles loaded in one latency window,
// converted to persistent f16x8 frags (32 VGPR). Loop: MFMA -> padded LDS tile
// (stride 68) -> lane=g logits/ev code (unchanged from R8).
__global__ __launch_bounds__(256) void k_edge_mfma(const float* __restrict__ fe,
                                                   const float* __restrict__ Weqk,
                                                   const float* __restrict__ Wev,
                                                   const __half* __restrict__ qh,
                                                   const __half* __restrict__ kh,
                                                   const int* __restrict__ eids,
                                                   const int* __restrict__ dsts,
                                                   const int* __restrict__ srcs,
                                                   __half* __restrict__ evh,
                                                   float* __restrict__ logw,
                                                   unsigned* __restrict__ lmax) {
  __shared__ float ldsbuf[4 * 2176];  // per wave: eq[16][68] + ev[16][68], 34.8 KB
  int lane = threadIdx.x & 63;
  int wid = threadIdx.x >> 6;
  int r16 = lane & 15;  // A-row (m) / B,D col-within-tile
  int kg = lane >> 4;   // k-group
  // B fragments (loaded once): [mat][ct][ks], k = ks*32 + kg*8 + j
  f16x8 bfrag[2][4][2];
#pragma unroll
  for (int ct = 0; ct < 4; ct++) {
#pragma unroll
    for (int ks = 0; ks < 2; ks++) {
      f16x8 bq, bv;
#pragma unroll
      for (int j = 0; j < 8; j++) {
        int k = ks * 32 + kg * 8 + j;
        bq[j] = (_Float16)Weqk[(size_t)k * 64 + ct * 16 + r16];
        bv[j] = (_Float16)Wev[(size_t)k * 64 + ct * 16 + r16];
      }
      bfrag[0][ct][ks] = bq;
      bfrag[1][ct][ks] = bv;
    }
  }
  float* lq = ldsbuf + wid * 2176;
  float* lv = ldsbuf + wid * 2176 + 1088;
  int mclamp = (r16 < 9) ? r16 : 8;  // pad rows recompute row 8, outputs ignored
  int s0 = (blockIdx.x * 4 + wid) * 4;  // 4500 blocks x 4 waves x 4 slots = 72000
  // ---- prologue: metadata + all 4 A tiles in one latency window ----
  int ee[4], dd[4], rr[4];
#pragma unroll
  for (int i = 0; i < 4; i++) {
    ee[i] = __builtin_amdgcn_readfirstlane(eids[s0 + i]);
    dd[i] = __builtin_amdgcn_readfirstlane(dsts[s0 + i]);
    rr[i] = __builtin_amdgcn_readfirstlane(srcs[s0 + i]);
  }
  f16x8 af[4][2];
#pragma unroll
  for (int i = 0; i < 4; i++) {
    const float* feb = fe + (size_t)ee[i] * 576 + mclamp * 64 + kg * 8;
    float4 p0 = *(const float4*)(feb);
    float4 p1 = *(const float4*)(feb + 4);
    float4 p2 = *(const float4*)(feb + 32);
    float4 p3 = *(const float4*)(feb + 36);
    af[i][0] = cvt8(p0, p1);
    af[i][1] = cvt8(p2, p3);
  }
  // ---- per-slot: MFMA -> LDS reshape -> logits/ev ----
#pragma unroll
  for (int ss = 0; ss < 4; ss++) {
    int s = s0 + ss;
#pragma unroll
    for (int ct = 0; ct < 4; ct++) {
      f32x4 zq = {0.f, 0.f, 0.f, 0.f};
      zq = __builtin_amdgcn_mfma_f32_16x16x32_f16(af[ss][0], bfrag[0][ct][0], zq, 0, 0, 0);
      zq = __builtin_amdgcn_mfma_f32_16x16x32_f16(af[ss][1], bfrag[0][ct][1], zq, 0, 0, 0);
      f32x4 zv = {0.f, 0.f, 0.f, 0.f};
      zv = __builtin_amdgcn_mfma_f32_16x16x32_f16(af[ss][0], bfrag[1][ct][0], zv, 0, 0, 0);
      zv = __builtin_amdgcn_mfma_f32_16x16x32_f16(af[ss][1], bfrag[1][ct][1], zv, 0, 0, 0);
      // D: row = kg*4 + reg, col = ct*16 + r16
#pragma unroll
      for (int reg = 0; reg < 4; reg++) {
        lq[(kg * 4 + reg) * 68 + ct * 16 + r16] = zq[reg];
        lv[(kg * 4 + reg) * 68 + ct * 16 + r16] = zv[reg];
      }
    }
    // same-wave LDS RAW: DS ops complete in issue order per wave
    const __half* qb = qh + (size_t)dd[ss] * 1152 + lane;
    const __half* kb = kh + (size_t)rr[ss] * 1152 + lane;
    float lacc = 0.f;
#pragma unroll
    for (int m = 0; m < 9; m++) {
      float eqv = lq[m * 68 + lane];
      evh[(size_t)s * 576 + m * 64 + lane] = __float2half(lv[m * 68 + lane]);
      float qk = __half2float(qb[m * 64]) * __half2float(kb[m * 64]) +
                 __half2float(qb[m * 64 + 576]) * __half2float(kb[m * 64 + 576]);
      lacc += eqv * qk;
    }
    lacc *= 0.05892556509887896f;  // 1/sqrt(P*M*DH)=1/sqrt(288)
    lacc += __shfl_xor(lacc, 8, 64);
    lacc += __shfl_xor(lacc, 4, 64);
    lacc += __shfl_xor(lacc, 2, 64);
    lacc += __shfl_xor(lacc, 1, 64);
    if ((lane & 15) == 0) {
      int h = lane >> 4;
      logw[(size_t)s * 4 + h] = lacc;
      atomicMax(lmax + (size_t)dd[ss] * 4 + h, fenc(lacc));
    }
  }
}

// ---------------- K5: w = exp(logit - lmax)*cutoff (slot order), denom sum ----------
__global__ __launch_bounds__(256) void k_expw2(float* __restrict__ logw,
                                               const unsigned* __restrict__ lmax,
                                               const int* __restrict__ dsts,
                                               const float* __restrict__ cuts,
                                               float* __restrict__ denom) {
  int t = blockIdx.x * 256 + threadIdx.x;  // exact E*4
  int s = t >> 2, h = t & 3;
  int dst = dsts[s];
  float wv = expf(logw[t] - fdec(lmax[(size_t)dst * 4 + h])) * cuts[s];
  logw[t] = wv;
  unsafeAtomicAdd(denom + (size_t)dst * 4 + h, wv);
}

// ---------------- K6: CSR gather aggregation, wave per dst, coalesced fp16 ----------
__global__ __launch_bounds__(256) void k_fagg2(const __half* __restrict__ evh,
                                               const __half* __restrict__ vh,
                                               const int* __restrict__ srcs,
                                               const int* __restrict__ rowptr,
                                               const float* __restrict__ logw,
                                               const float* __restrict__ denom,
                                               float* __restrict__ attn_out) {
  int dst = (blockIdx.x * 256 + threadIdx.x) >> 6;  // exact 6000 (1500 blocks)
  int g = threadIdx.x & 63;
  int e0 = __builtin_amdgcn_readfirstlane(rowptr[dst]);
  int e1 = __builtin_amdgcn_readfirstlane(rowptr[dst + 1]);
  float invd = 1.f / (denom[(size_t)dst * 4 + (g >> 4)] + 1e-9f);
  float acc[18];
#pragma unroll
  for (int i = 0; i < 18; i++) acc[i] = 0.f;
  for (int s = e0; s < e1; s++) {
    float attn = logw[(size_t)s * 4 + (g >> 4)] * invd;
    int src = __builtin_amdgcn_readfirstlane(srcs[s]);
    const __half* eb = evh + (size_t)s * 576 + g;
    const __half* vb = vh + (size_t)src * 1152 + g;
#pragma unroll
    for (int m = 0; m < 9; m++) {
      float sc = attn * __half2float(eb[m * 64]);
      acc[m] += sc * __half2float(vb[m * 64]);
      acc[m + 9] += sc * __half2float(vb[m * 64 + 576]);
    }
  }
  float* ob = attn_out + (size_t)dst * 1152 + g;
#pragma unroll
  for (int m = 0; m < 9; m++) {
    ob[m * 64] = acc[m];
    ob[m * 64 + 576] = acc[m + 9];
  }
}

// ---------------- K7: LDS-tiled Wo projection + post-select + gate + residual -------
__global__ __launch_bounds__(256) void k_wo_post3(const float* __restrict__ attn_out,
                                                  const float* __restrict__ Wo,
                                                  const float* __restrict__ xpre,
                                                  const float* __restrict__ fnodes,
                                                  const float* __restrict__ c,
                                                  const float* __restrict__ cnt,
                                                  const float* __restrict__ cutsum,
                                                  float* __restrict__ out) {
  __shared__ __align__(16) float xt[16 * 64];  // 4 KB
  int pm = blockIdx.y;
  int p = pm / 9, dm = deg_of(pm % 9);
  int n0 = blockIdx.x * 16;
  int g = threadIdx.x & 63, w = threadIdx.x >> 6;
  for (int i = threadIdx.x; i < 1024; i += 256) {
    int r = i >> 6, f = i & 63;
    xt[i] = attn_out[((size_t)(n0 + r) * 18 + pm) * 64 + f];
  }
  const float* Wb = Wo + (size_t)(p * 3 + dm) * 4096;
  float wreg[64];
#pragma unroll
  for (int f = 0; f < 64; f++) wreg[f] = Wb[f * 64 + g];
  __syncthreads();
  for (int i = 0; i < 4; i++) {
    int r = w * 4 + i;
    int n = n0 + r;
    float acc = 0.f;
#pragma unroll
    for (int f4 = 0; f4 < 16; f4++) {
      float4 a = *(const float4*)(xt + r * 64 + f4 * 4);
      acc += a.x * wreg[4 * f4] + a.y * wreg[4 * f4 + 1] + a.z * wreg[4 * f4 + 2] +
             a.w * wreg[4 * f4 + 3];
    }
    float mc = cutsum[n] / fmaxf(cnt[n], 1.f);
    size_t idx = ((size_t)n * 18 + pm) * 64 + g;
    float post = (mc < 1e-5f) ? xpre[idx] : acc;
    float a1v = c[(size_t)n * 1664 + 448 + (p * 3 + dm) * 64 + g];
    out[idx] = fnodes[idx] + a1v * post;
  }
}

// ---------------- K9a: h_pre[n][pm][j] = x@W1 (un-gated), (375,18) grid ------------
__global__ __launch_bounds__(256) void k_mlp1v2(const float* __restrict__ xp2,
                                                const float* __restrict__ W1,
                                                float* __restrict__ h) {
  __shared__ __align__(16) float xt[16 * 64];  // 4 KB
  int pm = blockIdx.y;
  int p = pm / 9, dm = deg_of(pm % 9);
  int n0 = blockIdx.x * 16;
  int w = threadIdx.x >> 6, g = threadIdx.x & 63;
  const float* w1b = W1 + (size_t)(p * 3 + dm) * 16384;
  float w1reg[64];
#pragma unroll
  for (int f = 0; f < 64; f++) w1reg[f] = w1b[(size_t)f * 256 + w * 64 + g];
  for (int i = threadIdx.x; i < 1024; i += 256) {
    int r = i >> 6, f = i & 63;
    xt[i] = xp2[((size_t)(n0 + r) * 18 + pm) * 64 + f];
  }
  __syncthreads();
  for (int r = 0; r < 16; r++) {
    float a0 = 0.f, a1 = 0.f, a2 = 0.f, a3 = 0.f;  // 4 chains to hide FMA latency
#pragma unroll
    for (int f4 = 0; f4 < 16; f4 += 4) {
      float4 x0 = *(const float4*)(xt + r * 64 + f4 * 4);
      float4 x1 = *(const float4*)(xt + r * 64 + f4 * 4 + 4);
      float4 x2 = *(const float4*)(xt + r * 64 + f4 * 4 + 8);
      float4 x3 = *(const float4*)(xt + r * 64 + f4 * 4 + 12);
      a0 += x0.x * w1reg[4 * f4] + x0.y * w1reg[4 * f4 + 1] + x0.z * w1reg[4 * f4 + 2] +
            x0.w * w1reg[4 * f4 + 3];
      a1 += x1.x * w1reg[4 * f4 + 4] + x1.y * w1reg[4 * f4 + 5] +
            x1.z * w1reg[4 * f4 + 6] + x1.w * w1reg[4 * f4 + 7];
      a2 += x2.x * w1reg[4 * f4 + 8] + x2.y * w1reg[4 * f4 + 9] +
            x2.z * w1reg[4 * f4 + 10] + x2.w * w1reg[4 * f4 + 11];
      a3 += x3.x * w1reg[4 * f4 + 12] + x3.y * w1reg[4 * f4 + 13] +
            x3.z * w1reg[4 * f4 + 14] + x3.w * w1reg[4 * f4 + 15];
    }
    // coalesced store: h[n][pm][j], j = w*64+g
    h[((size_t)(n0 + r) * 18 + pm) * 256 + w * 64 + g] = (a0 + a1) + (a2 + a3);
  }
}

// ---------------- K9b: gate[n][j] = gelu(s)/s from h_pre[n,pm=0,:], elementwise -----
__global__ __launch_bounds__(256) void k_gate2(const float* __restrict__ h,
                                               float* __restrict__ gatebuf) {
  int n = blockIdx.x;  // 6000 blocks
  int j = threadIdx.x;
  float s = h[(size_t)n * 4608 + j];
  float gt = (fabsf(s) > 1e-4f)
                 ? 0.5f * (1.f + tanhf(0.7978845608028654f * (s + 0.044715f * s * s * s)))
                 : 0.5f;
  gatebuf[(size_t)n * 256 + j] = gt;
}

// ---------------- K9c: out += a2 * ((h_pre*gate) @ W2), (375,18) grid ---------------
__global__ __launch_bounds__(256) void k_mlp2v2(const float* __restrict__ h,
                                                const float* __restrict__ W2,
                                                const float* __restrict__ gatebuf,
                                                const float* __restrict__ c,
                                                float* __restrict__ out) {
  __shared__ __align__(16) float ht[16 * 256];  // 16 KB
  __shared__ float po[4][16 * 64];              // 16 KB
  int pm = blockIdx.y;
  int p = pm / 9, dm = deg_of(pm % 9);
  int n0 = blockIdx.x * 16;
  int w = threadIdx.x >> 6, g = threadIdx.x & 63;
  const float* w2b = W2 + (size_t)(p * 3 + dm) * 16384;
  float w2reg[64];
#pragma unroll
  for (int k = 0; k < 64; k++) w2reg[k] = w2b[(size_t)(w * 64 + k) * 64 + g];
  for (int i = threadIdx.x; i < 4096; i += 256) {  // stage gated h tile, coalesced
    int r = i >> 8, k = i & 255;
    ht[i] = h[((size_t)(n0 + r) * 18 + pm) * 256 + k] *
            gatebuf[(size_t)(n0 + r) * 256 + k];
  }
  __syncthreads();
  for (int r = 0; r < 16; r++) {
    float a0 = 0.f, a1 = 0.f, a2 = 0.f, a3 = 0.f;
#pragma unroll
    for (int k4 = 0; k4 < 16; k4 += 4) {
      float4 h0 = *(const float4*)(ht + r * 256 + w * 64 + k4 * 4);
      float4 h1 = *(const float4*)(ht + r * 256 + w * 64 + k4 * 4 + 4);
      float4 h2 = *(const float4*)(ht + r * 256 + w * 64 + k4 * 4 + 8);
      float4 h3 = *(const float4*)(ht + r * 256 + w * 64 + k4 * 4 + 12);
      a0 += h0.x * w2reg[4 * k4] + h0.y * w2reg[4 * k4 + 1] + h0.z * w2reg[4 * k4 + 2] +
            h0.w * w2reg[4 * k4 + 3];
      a1 += h1.x * w2reg[4 * k4 + 4] + h1.y * w2reg[4 * k4 + 5] +
            h1.z * w2reg[4 * k4 + 6] + h1.w * w2reg[4 * k4 + 7];
      a2 += h2.x * w2reg[4 * k4 + 8] + h2.y * w2reg[4 * k4 + 9] +
            h2.z * w2reg[4 * k4 + 10] + h2.w * w2reg[4 * k4 + 11];
      a3 += h3.x * w2reg[4 * k4 + 12] + h3.y * w2reg[4 * k4 + 13] +
            h3.z * w2reg[4 * k4 + 14] + h3.w * w2reg[4 * k4 + 15];
    }
    po[w][r * 64 + g] = (a0 + a1) + (a2 + a3);
  }
  __syncthreads();
  for (int i = threadIdx.x; i < 1024; i += 256) {
    int r = i >> 6, gg = i & 63;
    float s2 = po[0][i] + po[1][i] + po[2][i] + po[3][i];
    int n = n0 + r;
    size_t idx = ((size_t)n * 18 + pm) * 64 + gg;
    out[idx] += c[(size_t)n * 1664 + 1280 + (p * 3 + dm) * 64 + gg] * s2;
  }
}

// ---------------- workspace layout (bytes) ----------------
#define OFF_C 0UL              // 39,936,000
#define OFF_XPRE 39936000UL    // 27,648,000 (reused as x_pre2)
#define OFF_QH 67584000UL      // 13,824,000 fp16 q
#define OFF_KH 81408000UL      // 13,824,000 fp16 k
#define OFF_VH 95232000UL      // 13,824,000 fp16 v
#define OFF_EVH 109056000UL    // 82,944,000 fp16 ev
#define OFF_ATTN 67584000UL    // 27,648,000 fp32 (over dead q+k after k_edge)
#define OFF_H 67584000UL       // 110,592,000 h_pre (over q,k,v,attn,ev — dead by MLP)
#define OFF_SBUF 192000000UL   // 1,536,000
#define OFF_LOGW 193536000UL   // 1,152,000
#define OFF_LMAX 194688000UL   // 96,000
#define OFF_DENOM 194784000UL  // 96,000
#define OFF_CNT 194880000UL    // 24,000
#define OFF_CUTSUM 194904000UL // 24,000
#define OFF_ROWPTR 194928000UL // 24,064
#define OFF_FILLC 194952064UL  // 24,000
#define OFF_EIDS 194976064UL   // 288,000
#define OFF_DSTS 195264064UL   // 288,000
#define OFF_SRCS 195552064UL   // 288,000
#define OFF_CUTS 195840064UL   // 288,000
#define OFF_GATE 196128064UL   // 6,144,000 (N x 256 fp32 gelu gate)
#define WS_NEEDED 202272064UL

extern "C" void kernel_launch(void* const* d_in, const int* in_sizes, int n_in,
                              void* d_out, int out_size, void* d_ws, size_t ws_size,
                              hipStream_t stream) {
  const float* f_nodes = (const float*)d_in[0];
  const float* f_edges = (const float*)d_in[1];
  const float* f_time = (const float*)d_in[2];
  const float* cutoff = (const float*)d_in[3];
  const float* ln_s = (const float*)d_in[4];
  const float* ln_b = (const float*)d_in[5];
  const float* W_c = (const float*)d_in[6];
  const float* b_c = (const float*)d_in[7];
  const float* Wq = (const float*)d_in[8];
  const float* Wk = (const float*)d_in[9];
  const float* Wv = (const float*)d_in[10];
  const float* Wo = (const float*)d_in[11];
  const float* We_qk = (const float*)d_in[12];
  const float* We_v = (const float*)d_in[13];
  const float* W1 = (const float*)d_in[14];
  const float* W2 = (const float*)d_in[15];
  const int* src_idx = (const int*)d_in[16];
  const int* dst_idx = (const int*)d_in[17];
  float* out = (float*)d_out;
  char* ws = (char*)d_ws;
  if (ws_size < WS_NEEDED) return;  // insufficient scratch; would show as poison absmax

  float* c = (float*)(ws + OFF_C);
  float* xpre = (float*)(ws + OFF_XPRE);
  __half* qh = (__half*)(ws + OFF_QH);
  __half* kh = (__half*)(ws + OFF_KH);
  __half* vh = (__half*)(ws + OFF_VH);
  __half* evh = (__half*)(ws + OFF_EVH);
  float* attn_out = (float*)(ws + OFF_ATTN);
  float* hbuf = (float*)(ws + OFF_H);
  float* sbuf = (float*)(ws + OFF_SBUF);
  float* logw = (float*)(ws + OFF_LOGW);
  unsigned* lmax = (unsigned*)(ws + OFF_LMAX);
  float* denom = (float*)(ws + OFF_DENOM);
  float* cnt = (float*)(ws + OFF_CNT);
  float* cutsum = (float*)(ws + OFF_CUTSUM);
  int* rowptr = (int*)(ws + OFF_ROWPTR);
  int* fillc = (int*)(ws + OFF_FILLC);
  int* eids = (int*)(ws + OFF_EIDS);
  int* dsts = (int*)(ws + OFF_DSTS);
  int* srcs = (int*)(ws + OFF_SRCS);
  float* cuts = (float*)(ws + OFF_CUTS);
  float* gatebuf = (float*)(ws + OFF_GATE);

  // zero lmax/denom/cnt/cutsum (contiguous)
  hipMemsetAsync(ws + OFF_LMAX, 0, 240000, stream);

  k_ln_t<<<1500, 256, 0, stream>>>(f_time, ln_s, ln_b, sbuf);
  k_count<<<282, 256, 0, stream>>>(dst_idx, cutoff, cnt, cutsum);
  k_cond_mm<<<750, 256, 0, stream>>>(sbuf, W_c, b_c, c);
  k_scan<<<1, 1024, 0, stream>>>(cnt, rowptr, fillc);
  k_fill<<<282, 256, 0, stream>>>(dst_idx, src_idx, cutoff, fillc, eids, dsts, srcs,
                                  cuts);
  k_lnmod<<<3000, 256, 0, stream>>>(f_nodes, c, xpre, 0, 384);

  k_qkv2<<<dim3(375, 18), 192, 0, stream>>>(xpre, Wq, Wk, Wv, qh, kh, vh);

  k_edge_mfma<<<4500, 256, 0, stream>>>(f_edges, We_qk, We_v, qh, kh, eids, dsts, srcs,
                                        evh, logw, lmax);
  k_expw2<<<1125, 256, 0, stream>>>(logw, lmax, dsts, cuts, denom);
  k_fagg2<<<1500, 256, 0, stream>>>(evh, vh, srcs, rowptr, logw, denom, attn_out);
  k_wo_post3<<<dim3(375, 18), 256, 0, stream>>>(attn_out, Wo, xpre, f_nodes, c, cnt,
                                                cutsum, out);

  k_lnmod<<<3000, 256, 0, stream>>>(out, c, xpre, 832, 1216);  // x_pre2 (buffer reuse)
  k_mlp1v2<<<dim3(375, 18), 256, 0, stream>>>(xpre, W1, hbuf);
  k_gate2<<<6000, 256, 0, stream>>>(hbuf, gatebuf);
  k_mlp2v2<<<dim3(375, 18), 256, 0, stream>>>(hbuf, W2, gatebuf, c, out);
}